// Round 10
// baseline (483.135 us; speedup 1.0000x reference)
//
#include <hip/hip_runtime.h>
#include <hip/hip_bf16.h>
#include <hip/hip_fp8.h>
#include <cstdint>
#include <cstddef>

typedef __bf16 bf16;
typedef bf16 bf16x4 __attribute__((ext_vector_type(4)));
typedef bf16 bf16x8 __attribute__((ext_vector_type(8)));
typedef float f32x4 __attribute__((ext_vector_type(4)));
typedef float f32x2 __attribute__((ext_vector_type(2)));

__device__ __forceinline__ float fp8_to_f32(uint8_t b) {
  __hip_fp8_e4m3 t; t.__x = (__hip_fp8_storage_t)b; return (float)t;
}
__device__ __forceinline__ uint8_t f32_to_fp8(float v) {
  __hip_fp8_e4m3 t(v); return (uint8_t)t.__x;
}

__device__ __forceinline__ void cvt4_fp8(int w, float* f) {
#if __has_builtin(__builtin_amdgcn_cvt_pk_f32_fp8)
  f32x2 a = __builtin_amdgcn_cvt_pk_f32_fp8(w, false);
  f32x2 b = __builtin_amdgcn_cvt_pk_f32_fp8(w, true);
  f[0] = a[0]; f[1] = a[1]; f[2] = b[0]; f[3] = b[1];
#else
  f[0] = fp8_to_f32((uint8_t)w);
  f[1] = fp8_to_f32((uint8_t)(w >> 8));
  f[2] = fp8_to_f32((uint8_t)(w >> 16));
  f[3] = fp8_to_f32((uint8_t)(w >> 24));
#endif
}

// ---------------- prep ----------------
__device__ __forceinline__ int kv_perm_to_orig(int j) {
  int jj = j & 255, h = jj >> 5, c = jj & 31;
  return h * 64 + ((j >> 8) ? 32 : 0) + c;
}

__global__ __launch_bounds__(256) void prep_kernel(
    const float* __restrict__ q_w, const float* __restrict__ kv_w,
    const float* __restrict__ proj_w, const float* __restrict__ fc1_w,
    const float* __restrict__ fc2_w, const float* __restrict__ q_b,
    const float* __restrict__ kv_b,
    bf16* __restrict__ wqkv, bf16* __restrict__ wproj,
    bf16* __restrict__ wfc1, bf16* __restrict__ wfc2,
    float* __restrict__ qscale, float* __restrict__ qbias)
{
  int i = blockIdx.x * 256 + threadIdx.x;
  if (i < 196608) {
    int row = i >> 8, col = i & 255;
    float v;
    if (row < 256) v = q_w[i];
    else           v = kv_w[kv_perm_to_orig(row - 256) * 256 + col];
    wqkv[i] = (bf16)v;
  }
  if (i < 65536)  wproj[i] = (bf16)proj_w[i];
  if (i < 131072) { wfc1[i] = (bf16)fc1_w[i]; wfc2[i] = (bf16)fc2_w[i]; }
  if (i < 768) {
    const float s = 0.17677669529663687f;  // 1/sqrt(32)
    if (i < 256) { qscale[i] = s;    qbias[i] = q_b[i] * s; }
    else         { qscale[i] = 1.0f; qbias[i] = kv_b[kv_perm_to_orig(i - 256)]; }
  }
}

// ---------------- layernorm ----------------
__global__ __launch_bounds__(256) void ln_kernel(
    const float* __restrict__ in, const float* __restrict__ w,
    const float* __restrict__ b, bf16* __restrict__ out)
{
  const int wv = threadIdx.x >> 6, lane = threadIdx.x & 63;
  const int row = blockIdx.x * 4 + wv;
  f32x4 v = *((const f32x4*)(in + (size_t)row * 256) + lane);
  float s  = v[0] + v[1] + v[2] + v[3];
  float s2 = v[0]*v[0] + v[1]*v[1] + v[2]*v[2] + v[3]*v[3];
  #pragma unroll
  for (int o = 1; o < 64; o <<= 1) { s += __shfl_xor(s, o); s2 += __shfl_xor(s2, o); }
  float mu = s * (1.0f / 256.0f);
  float var = s2 * (1.0f / 256.0f) - mu * mu;
  float rstd = rsqrtf(var + 1e-5f);
  f32x4 wv4 = *((const f32x4*)w + lane);
  f32x4 bv4 = *((const f32x4*)b + lane);
  bf16x4 o4;
  o4[0] = (bf16)((v[0] - mu) * rstd * wv4[0] + bv4[0]);
  o4[1] = (bf16)((v[1] - mu) * rstd * wv4[1] + bv4[1]);
  o4[2] = (bf16)((v[2] - mu) * rstd * wv4[2] + bv4[2]);
  o4[3] = (bf16)((v[3] - mu) * rstd * wv4[3] + bv4[3]);
  *((bf16x4*)(out + (size_t)row * 256) + lane) = o4;
}

// ---------------- GEMM: barrier-free K-loop; REPS>1 = probe mode ----------------
template<int NF, int K, int REPS>
__global__ __launch_bounds__(256) void gemm_bt(
    const bf16* __restrict__ A, const bf16* __restrict__ B,
    int N,
    const float* __restrict__ scale, const float* __restrict__ bias,
    const float* __restrict__ residual, int do_gelu,
    float* __restrict__ outf, bf16* __restrict__ outh,
    bf16* __restrict__ outq, uint8_t* __restrict__ outkv)
{
  constexpr int CN = NF * 16;
  constexpr int SPI = 64 / CN;
  __shared__ __align__(16) bf16 ldsB[K / 8][CN][8];
  const int tid = threadIdx.x;
  const int w = tid >> 6, lane = tid & 63;
  const int part = lane >> 4, r16 = lane & 15;
  const int rowBase = blockIdx.x * 64 + w * 16;
  const int colBase = blockIdx.y * CN;

  for (int s = w * SPI; s < K / 8; s += 4 * SPI) {
    const bf16* src = B + (size_t)(colBase + (lane & (CN - 1))) * K + (s + lane / CN) * 8;
    __builtin_amdgcn_global_load_lds(
        (const __attribute__((address_space(1))) uint32_t*)src,
        (__attribute__((address_space(3))) uint32_t*)&ldsB[s][0][0], 16, 0, 0);
  }

  const bf16* Aw = A + (size_t)(rowBase + r16) * K + part * 8;
  __syncthreads();

  for (int rep = 0; rep < REPS; ++rep) {
    f32x4 acc[NF] = {};
    #pragma unroll
    for (int p2 = 0; p2 < K / 32; ++p2) {
      bf16x8 af = *(const bf16x8*)(Aw + p2 * 32);
      bf16x8 bfr[NF];
      #pragma unroll
      for (int fn = 0; fn < NF; ++fn)
        bfr[fn] = *(const bf16x8*)&ldsB[p2 * 4 + part][fn * 16 + r16][0];
      #pragma unroll
      for (int fn = 0; fn < NF; ++fn)
        acc[fn] = __builtin_amdgcn_mfma_f32_16x16x32_bf16(af, bfr[fn], acc[fn], 0, 0, 0);
    }

    #pragma unroll
    for (int fn = 0; fn < NF; ++fn)
    #pragma unroll
    for (int r = 0; r < 4; ++r) {
      int row = rowBase + part * 4 + r;
      int col = colBase + fn * 16 + r16;
      float v = acc[fn][r];
      if (scale)    v *= scale[col];
      if (bias)     v += bias[col];
      if (do_gelu)  v = 0.5f * v * (1.0f + erff(v * 0.70710678118654752f));
      if (residual) v += residual[(size_t)row * N + col];
      if (outq) {
        if (col < 256) outq[(size_t)row * 256 + col] = (bf16)v;
        else           outkv[(size_t)row * 512 + (col - 256)] = f32_to_fp8(v);
      } else if (outf) {
        outf[(size_t)row * N + col] = v;
      } else {
        outh[(size_t)row * N + col] = (bf16)v;
      }
    }
  }
}

// ---------------- posm ----------------
__global__ __launch_bounds__(256) void posm_kernel(
    const int* __restrict__ pe_idx,
    const float* __restrict__ cluster_mask,
    const float* __restrict__ pre_table,
    const float* __restrict__ pe_w, const float* __restrict__ pe_b,
    float* __restrict__ posm)
{
  int i = blockIdx.x * 256 + threadIdx.x;
  int pj = pe_idx[i];
  const float* pt = pre_table + (size_t)pj * 5;
  float p0 = pt[0], p1 = pt[1], p2 = pt[2], p3 = pt[3], p4 = pt[4];
  float mk = (1.0f - cluster_mask[i]) * -100.0f;
  f32x4 lo, hi;
  #pragma unroll
  for (int h = 0; h < 8; ++h) {
    float v = p0 * pe_w[h*5+0] + p1 * pe_w[h*5+1] + p2 * pe_w[h*5+2]
            + p3 * pe_w[h*5+3] + p4 * pe_w[h*5+4] + pe_b[h] + mk;
    if (h < 4) lo[h] = v; else hi[h-4] = v;
  }
  *((f32x4*)(posm + (size_t)i * 8))     = lo;
  *((f32x4*)(posm + (size_t)i * 8 + 4)) = hi;
}

// ---------------- attention v2 (REPS>1 = probe mode, distinct tokens per rep) ----------------
template<int REPS>
__global__ __launch_bounds__(256) void attn_kernel(
    const bf16* __restrict__ qb,
    const uint8_t* __restrict__ kvf8,
    const int* __restrict__ member_idx,
    const float* __restrict__ posm,
    const float* __restrict__ blank_k, const float* __restrict__ blank_v,
    bf16* __restrict__ out)
{
  const int wv = threadIdx.x >> 6, lane = threadIdx.x & 63;
  const int token0 = blockIdx.x * 4 + wv;
  const int n = lane >> 3, h = lane & 7;

  for (int rep = 0; rep < REPS; ++rep) {
    const int token = token0 ^ (rep << 10);
    const int bb = token >> 12;

    float q[32];
    {
      const bf16* qrow = qb + (size_t)token * 256 + h * 32;
      #pragma unroll
      for (int c8 = 0; c8 < 4; ++c8) {
        bf16x8 t = *(const bf16x8*)(qrow + c8 * 8);
        #pragma unroll
        for (int e = 0; e < 8; ++e) q[c8 * 8 + e] = (float)t[e];
      }
    }

    int   midx[6];
    float pos[6];
    #pragma unroll
    for (int m = 0; m < 6; ++m) {
      midx[m] = member_idx[(size_t)token * 48 + m * 8 + n];
      pos[m]  = posm[(size_t)token * 384 + m * 64 + lane];
    }

    float l = 0.0f, o[32] = {};
    {
      float db = 0.0f;
      #pragma unroll
      for (int c4 = 0; c4 < 8; ++c4) {
        f32x4 bk = *((const f32x4*)(blank_k + h * 32) + c4);
        db += q[c4*4+0]*bk[0] + q[c4*4+1]*bk[1] + q[c4*4+2]*bk[2] + q[c4*4+3]*bk[3];
      }
      float pb = __expf(db);
      if (n == 0) {
        l = pb;
        #pragma unroll
        for (int c4 = 0; c4 < 8; ++c4) {
          f32x4 bv = *((const f32x4*)(blank_v + h * 32) + c4);
          o[c4*4+0] = pb*bv[0]; o[c4*4+1] = pb*bv[1];
          o[c4*4+2] = pb*bv[2]; o[c4*4+3] = pb*bv[3];
        }
      }
    }

    const uint8_t* kvb = kvf8 + (size_t)(bb * 4096) * 512;
    #pragma unroll
    for (int m = 0; m < 6; ++m) {
      const uint8_t* kp = kvb + (size_t)midx[m] * 512 + h * 32;
      int4 kw = *(const int4*)kp;
      int4 kx = *(const int4*)(kp + 16);
      int4 vw = *(const int4*)(kp + 256);
      int4 vx = *(const int4*)(kp + 272);

      float kf[8];
      float d = 0.0f;
      cvt4_fp8(kw.x, kf); cvt4_fp8(kw.y, kf + 4);
      #pragma unroll
      for (int c = 0; c < 8; ++c) d += q[c] * kf[c];
      cvt4_fp8(kw.z, kf); cvt4_fp8(kw.w, kf + 4);
      #pragma unroll
      for (int c = 0; c < 8; ++c) d += q[8 + c] * kf[c];
      cvt4_fp8(kx.x, kf); cvt4_fp8(kx.y, kf + 4);
      #pragma unroll
      for (int c = 0; c < 8; ++c) d += q[16 + c] * kf[c];
      cvt4_fp8(kx.z, kf); cvt4_fp8(kx.w, kf + 4);
      #pragma unroll
      for (int c = 0; c < 8; ++c) d += q[24 + c] * kf[c];

      float p = __expf(d + pos[m]);
      l += p;

      float vf[8];
      cvt4_fp8(vw.x, vf); cvt4_fp8(vw.y, vf + 4);
      #pragma unroll
      for (int c = 0; c < 8; ++c) o[c] += p * vf[c];
      cvt4_fp8(vw.z, vf); cvt4_fp8(vw.w, vf + 4);
      #pragma unroll
      for (int c = 0; c < 8; ++c) o[8 + c] += p * vf[c];
      cvt4_fp8(vx.x, vf); cvt4_fp8(vx.y, vf + 4);
      #pragma unroll
      for (int c = 0; c < 8; ++c) o[16 + c] += p * vf[c];
      cvt4_fp8(vx.z, vf); cvt4_fp8(vx.w, vf + 4);
      #pragma unroll
      for (int c = 0; c < 8; ++c) o[24 + c] += p * vf[c];
    }

    #pragma unroll
    for (int off = 8; off < 64; off <<= 1) {
      l += __shfl_xor(l, off);
      #pragma unroll
      for (int c = 0; c < 32; ++c) o[c] += __shfl_xor(o[c], off);
    }

    if (n == 0) {
      float inv = 1.0f / l;
      bf16* orow = out + (size_t)token * 256 + h * 32;
      #pragma unroll
      for (int c8 = 0; c8 < 4; ++c8) {
        bf16x8 t;
        #pragma unroll
        for (int e = 0; e < 8; ++e) t[e] = (bf16)(o[c8 * 8 + e] * inv);
        *(bf16x8*)(orow + c8 * 8) = t;
      }
    }
  }
}

// ---------------- host launcher ----------------
extern "C" void kernel_launch(void* const* d_in, const int* in_sizes, int n_in,
                              void* d_out, int out_size, void* d_ws, size_t ws_size,
                              hipStream_t stream)
{
  (void)in_sizes; (void)n_in; (void)out_size; (void)ws_size;
  const float* feat         = (const float*)d_in[0];
  const float* cluster_mask = (const float*)d_in[1];
  const float* pre_table    = (const float*)d_in[2];
  const float* norm1_w      = (const float*)d_in[3];
  const float* norm1_b      = (const float*)d_in[4];
  const float* q_w    = (const float*)d_in[5];
  const float* q_b    = (const float*)d_in[6];
  const float* kv_w   = (const float*)d_in[7];
  const float* kv_b   = (const float*)d_in[8];
  const float* blank_k = (const float*)d_in[9];
  const float* blank_v = (const float*)d_in[10];
  const float* pe_w   = (const float*)d_in[11];
  const float* pe_b   = (const float*)d_in[12];
  const float* proj_w = (const float*)d_in[13];
  const float* proj_b = (const float*)d_in[14];
  const float* norm2_w = (const float*)d_in[15];
  const float* norm2_b = (const float*)d_in[16];
  const float* fc1_w  = (const float*)d_in[17];
  const float* fc1_b  = (const float*)d_in[18];
  const float* fc2_w  = (const float*)d_in[19];
  const float* fc2_b  = (const float*)d_in[20];
  const int* member_idx = (const int*)d_in[21];
  const int* pe_idx     = (const int*)d_in[22];

  char* ws = (char*)d_ws;
  size_t off = 0;
  auto alloc = [&](size_t bytes) -> void* {
    void* p = ws + off; off += (bytes + 255) & ~(size_t)255; return p;
  };
  bf16*  wqkv  = (bf16*)alloc(768 * 256 * sizeof(bf16));
  bf16*  wproj = (bf16*)alloc(256 * 256 * sizeof(bf16));
  bf16*  wfc1  = (bf16*)alloc(512 * 256 * sizeof(bf16));
  bf16*  wfc2  = (bf16*)alloc(256 * 512 * sizeof(bf16));
  float* qscale = (float*)alloc(768 * sizeof(float));
  float* qbias  = (float*)alloc(768 * sizeof(float));
  bf16*    xbuf = (bf16*)alloc((size_t)8192 * 256 * sizeof(bf16));
  bf16*    qb   = (bf16*)alloc((size_t)8192 * 256 * sizeof(bf16));
  uint8_t* kvf8 = (uint8_t*)alloc((size_t)8192 * 512);
  bf16*    y1   = (bf16*)alloc((size_t)8192 * 512 * sizeof(bf16));
  bf16*  attnb = (bf16*)alloc((size_t)8192 * 256 * sizeof(bf16));
  float* feat2 = (float*)alloc((size_t)8192 * 256 * sizeof(float));
  float* posm  = (float*)alloc((size_t)8192 * 48 * 8 * sizeof(float));
  // probe scratch sinks (never read; overwritten freely)
  bf16*    pscr_h  = (bf16*)alloc((size_t)8192 * 512 * sizeof(bf16));
  float*   pscr_f  = (float*)alloc((size_t)8192 * 256 * sizeof(float));
  uint8_t* pscr_kv = (uint8_t*)alloc((size_t)8192 * 512);
  float* outf = (float*)d_out;

  // ---- real pipeline (identical to round 9) ----
  prep_kernel<<<dim3(768), dim3(256), 0, stream>>>(
      q_w, kv_w, proj_w, fc1_w, fc2_w, q_b, kv_b,
      wqkv, wproj, wfc1, wfc2, qscale, qbias);
  posm_kernel<<<dim3(1536), dim3(256), 0, stream>>>(
      pe_idx, cluster_mask, pre_table, pe_w, pe_b, posm);
  ln_kernel<<<dim3(2048), dim3(256), 0, stream>>>(feat, norm1_w, norm1_b, xbuf);
  gemm_bt<4, 256, 1><<<dim3(128, 12), dim3(256), 0, stream>>>(
      xbuf, wqkv, 768, qscale, qbias, (const float*)nullptr, 0,
      (float*)nullptr, (bf16*)nullptr, qb, kvf8);
  attn_kernel<1><<<dim3(2048), dim3(256), 0, stream>>>(
      qb, kvf8, member_idx, posm, blank_k, blank_v, attnb);
  gemm_bt<2, 256, 1><<<dim3(128, 8), dim3(256), 0, stream>>>(
      attnb, wproj, 256, (const float*)nullptr, proj_b,
      feat, 0, feat2, (bf16*)nullptr, (bf16*)nullptr, (uint8_t*)nullptr);
  ln_kernel<<<dim3(2048), dim3(256), 0, stream>>>(feat2, norm2_w, norm2_b, xbuf);
  gemm_bt<4, 256, 1><<<dim3(128, 8), dim3(256), 0, stream>>>(
      xbuf, wfc1, 512, (const float*)nullptr, fc1_b,
      (const float*)nullptr, 1, (float*)nullptr, y1, (bf16*)nullptr, (uint8_t*)nullptr);
  gemm_bt<2, 512, 1><<<dim3(128, 8), dim3(256), 0, stream>>>(
      y1, wfc2, 256, (const float*)nullptr, fc2_b,
      feat2, 0, outf, (bf16*)nullptr, (bf16*)nullptr, (uint8_t*)nullptr);

  // ---- diagnostic probes (after pipeline; write scratch only; d_out untouched) ----
  // QKV x4
  gemm_bt<4, 256, 4><<<dim3(128, 12), dim3(256), 0, stream>>>(
      xbuf, wqkv, 768, qscale, qbias, (const float*)nullptr, 0,
      (float*)nullptr, (bf16*)nullptr, pscr_h, pscr_kv);
  // proj x8
  gemm_bt<2, 256, 8><<<dim3(128, 8), dim3(256), 0, stream>>>(
      attnb, wproj, 256, (const float*)nullptr, proj_b,
      feat, 0, pscr_f, (bf16*)nullptr, (bf16*)nullptr, (uint8_t*)nullptr);
  // fc1 x6
  gemm_bt<4, 256, 6><<<dim3(128, 8), dim3(256), 0, stream>>>(
      xbuf, wfc1, 512, (const float*)nullptr, fc1_b,
      (const float*)nullptr, 1, (float*)nullptr, pscr_h, (bf16*)nullptr, (uint8_t*)nullptr);
  // fc2 x6
  gemm_bt<2, 512, 6><<<dim3(128, 8), dim3(256), 0, stream>>>(
      y1, wfc2, 256, (const float*)nullptr, fc2_b,
      feat2, 0, pscr_f, (bf16*)nullptr, (bf16*)nullptr, (uint8_t*)nullptr);
  // attn x4
  attn_kernel<4><<<dim3(2048), dim3(256), 0, stream>>>(
      qb, kvf8, member_idx, posm, blank_k, blank_v, pscr_h);
}

// Round 11
// 160.456 us; speedup vs baseline: 3.0110x; 3.0110x over previous
//
#include <hip/hip_runtime.h>
#include <hip/hip_bf16.h>
#include <cstdint>
#include <cstddef>

typedef __bf16 bf16;
typedef bf16 bf16x8 __attribute__((ext_vector_type(8)));
typedef bf16 bf16x4 __attribute__((ext_vector_type(4)));
typedef float f32x4 __attribute__((ext_vector_type(4)));
typedef _Float16 h16;
typedef h16 h16x2 __attribute__((ext_vector_type(2)));
typedef h16 h16x8 __attribute__((ext_vector_type(8)));

// ---------------- fused prep (weights->bf16) + posm (pe gather) ----------------
// kv activation col 256+j: j<256 -> k[h=j>>5][c=j&31]; j>=256 -> v[h][c].
__device__ __forceinline__ int kv_perm_to_orig(int j) {
  int jj = j & 255, h = jj >> 5, c = jj & 31;
  return h * 64 + ((j >> 8) ? 32 : 0) + c;
}

__global__ __launch_bounds__(256) void prep_posm_kernel(
    const float* __restrict__ q_w, const float* __restrict__ kv_w,
    const float* __restrict__ proj_w, const float* __restrict__ fc1_w,
    const float* __restrict__ fc2_w, const float* __restrict__ q_b,
    const float* __restrict__ kv_b,
    bf16* __restrict__ wqkv, bf16* __restrict__ wproj,
    bf16* __restrict__ wfc1, bf16* __restrict__ wfc2,
    float* __restrict__ qscale, float* __restrict__ qbias,
    const int* __restrict__ pe_idx,
    const float* __restrict__ cluster_mask,
    const float* __restrict__ pre_table,
    const float* __restrict__ pe_w, const float* __restrict__ pe_b,
    float* __restrict__ posm)
{
  const int b = blockIdx.x;
  if (b < 768) {
    int i = b * 256 + threadIdx.x;
    if (i < 196608) {
      int row = i >> 8, col = i & 255;
      float v;
      if (row < 256) v = q_w[i];
      else           v = kv_w[kv_perm_to_orig(row - 256) * 256 + col];
      wqkv[i] = (bf16)v;
    }
    if (i < 65536)  wproj[i] = (bf16)proj_w[i];
    if (i < 131072) { wfc1[i] = (bf16)fc1_w[i]; wfc2[i] = (bf16)fc2_w[i]; }
    if (i < 768) {
      const float s = 0.17677669529663687f;  // 1/sqrt(32)
      if (i < 256) { qscale[i] = s;    qbias[i] = q_b[i] * s; }
      else         { qscale[i] = 1.0f; qbias[i] = kv_b[kv_perm_to_orig(i - 256)]; }
    }
  } else {
    int i = (b - 768) * 256 + threadIdx.x;   // (token, j) flat, < 393216
    int pj = pe_idx[i];
    const float* pt = pre_table + (size_t)pj * 5;
    float p0 = pt[0], p1 = pt[1], p2 = pt[2], p3 = pt[3], p4 = pt[4];
    float mk = (1.0f - cluster_mask[i]) * -100.0f;
    f32x4 lo, hi;
    #pragma unroll
    for (int h = 0; h < 8; ++h) {
      float v = p0 * pe_w[h*5+0] + p1 * pe_w[h*5+1] + p2 * pe_w[h*5+2]
              + p3 * pe_w[h*5+3] + p4 * pe_w[h*5+4] + pe_b[h] + mk;
      if (h < 4) lo[h] = v; else hi[h-4] = v;
    }
    *((f32x4*)(posm + (size_t)i * 8))     = lo;
    *((f32x4*)(posm + (size_t)i * 8 + 4)) = hi;
  }
}

// ---------------- GEMM: C(M,N) = A(M,K) * B(N,K)^T — barrier-free K-loop ----------------
// LNA: A is f32 and layernorm (lnw,lnb) is applied on the fly. Each lane owns exactly
// one A-row (rowBase + r16); stats via 64-f32 read + shfl_xor(16,32) across part-groups.
// Outputs: (outq,outkv) = split f16 q/kv, else outf (f32) else outh (bf16).
template<int NF, int K, bool LNA>
__global__ __launch_bounds__(256) void gemm_bt(
    const void* __restrict__ Av, const bf16* __restrict__ B,
    int N,
    const float* __restrict__ lnw, const float* __restrict__ lnb,
    const float* __restrict__ scale, const float* __restrict__ bias,
    const float* __restrict__ residual, int do_gelu,
    float* __restrict__ outf, bf16* __restrict__ outh,
    h16* __restrict__ outq, h16* __restrict__ outkv)
{
  constexpr int CN = NF * 16;
  constexpr int SPI = 64 / CN;
  __shared__ __align__(16) bf16 ldsB[K / 8][CN][8];
  __shared__ float ldsNW[256], ldsNB[256];
  const int tid = threadIdx.x;
  const int w = tid >> 6, lane = tid & 63;
  const int part = lane >> 4, r16 = lane & 15;
  const int rowBase = blockIdx.x * 64 + w * 16;
  const int colBase = blockIdx.y * CN;

  for (int s = w * SPI; s < K / 8; s += 4 * SPI) {
    const bf16* src = B + (size_t)(colBase + (lane & (CN - 1))) * K + (s + lane / CN) * 8;
    __builtin_amdgcn_global_load_lds(
        (const __attribute__((address_space(1))) uint32_t*)src,
        (__attribute__((address_space(3))) uint32_t*)&ldsB[s][0][0], 16, 0, 0);
  }
  if constexpr (LNA) {
    if (tid < 256) { ldsNW[tid] = lnw[tid]; ldsNB[tid] = lnb[tid]; }
  }

  const float* rowp = nullptr;
  const bf16* Aw = nullptr;
  float mu = 0.0f, rstd = 0.0f;
  if constexpr (LNA) {
    rowp = (const float*)Av + (size_t)(rowBase + r16) * K;
    float s = 0.0f, s2 = 0.0f;
    #pragma unroll
    for (int c4 = 0; c4 < K / 16; ++c4) {
      f32x4 v = *((const f32x4*)(rowp + part * (K / 4)) + c4);
      s  += v[0] + v[1] + v[2] + v[3];
      s2 += v[0]*v[0] + v[1]*v[1] + v[2]*v[2] + v[3]*v[3];
    }
    s += __shfl_xor(s, 16); s2 += __shfl_xor(s2, 16);
    s += __shfl_xor(s, 32); s2 += __shfl_xor(s2, 32);
    mu = s * (1.0f / K);
    float var = s2 * (1.0f / K) - mu * mu;
    rstd = rsqrtf(var + 1e-5f);
  } else {
    Aw = (const bf16*)Av + (size_t)(rowBase + r16) * K + part * 8;
  }
  __syncthreads();

  f32x4 acc[NF] = {};
  #pragma unroll
  for (int p2 = 0; p2 < K / 32; ++p2) {
    bf16x8 af;
    if constexpr (LNA) {
      const float* ap = rowp + p2 * 32 + part * 8;
      f32x4 a0 = *(const f32x4*)ap;
      f32x4 a1 = *(const f32x4*)(ap + 4);
      const int cb = p2 * 32 + part * 8;
      f32x4 w0 = *(const f32x4*)&ldsNW[cb];
      f32x4 w1 = *(const f32x4*)&ldsNW[cb + 4];
      f32x4 b0 = *(const f32x4*)&ldsNB[cb];
      f32x4 b1 = *(const f32x4*)&ldsNB[cb + 4];
      #pragma unroll
      for (int e = 0; e < 4; ++e) {
        af[e]     = (bf16)((a0[e] - mu) * rstd * w0[e] + b0[e]);
        af[4 + e] = (bf16)((a1[e] - mu) * rstd * w1[e] + b1[e]);
      }
    } else {
      af = *(const bf16x8*)(Aw + p2 * 32);
    }
    bf16x8 bfr[NF];
    #pragma unroll
    for (int fn = 0; fn < NF; ++fn)
      bfr[fn] = *(const bf16x8*)&ldsB[p2 * 4 + part][fn * 16 + r16][0];
    #pragma unroll
    for (int fn = 0; fn < NF; ++fn)
      acc[fn] = __builtin_amdgcn_mfma_f32_16x16x32_bf16(af, bfr[fn], acc[fn], 0, 0, 0);
  }

  #pragma unroll
  for (int fn = 0; fn < NF; ++fn)
  #pragma unroll
  for (int r = 0; r < 4; ++r) {
    int row = rowBase + part * 4 + r;
    int col = colBase + fn * 16 + r16;
    float v = acc[fn][r];
    if (scale)    v *= scale[col];
    if (bias)     v += bias[col];
    if (do_gelu)  v = 0.5f * v * (1.0f + erff(v * 0.70710678118654752f));
    if (residual) v += residual[(size_t)row * N + col];
    if (outq) {
      if (col < 256) outq[(size_t)row * 256 + col] = (h16)v;
      else           outkv[(size_t)row * 512 + (col - 256)] = (h16)v;
    } else if (outf) {
      outf[(size_t)row * N + col] = v;
    } else {
      outh[(size_t)row * N + col] = (bf16)v;
    }
  }
}

// ---------------- attention v3: wave per token, lane = (n, h); f16 KV, fdot2 ----------------
__global__ __launch_bounds__(256) void attn_kernel(
    const h16* __restrict__ qf,
    const h16* __restrict__ kvf,
    const int* __restrict__ member_idx,
    const float* __restrict__ posm,
    const float* __restrict__ blank_k, const float* __restrict__ blank_v,
    bf16* __restrict__ out)
{
  const int wv = threadIdx.x >> 6, lane = threadIdx.x & 63;
  const int token = blockIdx.x * 4 + wv;
  const int bb = token >> 12;
  const int n = lane >> 3, h = lane & 7;

  // q packed f16 (16 VGPR)
  h16x8 q8[4];
  {
    const h16x8* qrow = (const h16x8*)(qf + (size_t)token * 256 + h * 32);
    #pragma unroll
    for (int i = 0; i < 4; ++i) q8[i] = qrow[i];
  }

  int   midx[6];
  float pos[6];
  #pragma unroll
  for (int m = 0; m < 6; ++m) {
    midx[m] = member_idx[(size_t)token * 48 + m * 8 + n];
    pos[m]  = posm[(size_t)token * 384 + m * 64 + lane];
  }

  float l = 0.0f, o[32] = {};
  {  // blank token seeds group n==0
    float db = 0.0f;
    #pragma unroll
    for (int i = 0; i < 4; ++i) {
      f32x4 bk0 = *((const f32x4*)(blank_k + h * 32) + i * 2);
      f32x4 bk1 = *((const f32x4*)(blank_k + h * 32) + i * 2 + 1);
      #pragma unroll
      for (int e = 0; e < 4; ++e) {
        db += (float)q8[i][e]     * bk0[e];
        db += (float)q8[i][4 + e] * bk1[e];
      }
    }
    float pb = __expf(db);
    if (n == 0) {
      l = pb;
      #pragma unroll
      for (int c = 0; c < 32; ++c) o[c] = pb * blank_v[h * 32 + c];
    }
  }

  const h16* kvb = kvf + (size_t)(bb * 4096) * 512;
  #pragma unroll
  for (int m = 0; m < 6; ++m) {
    const h16* kp = kvb + (size_t)midx[m] * 512 + h * 32;
    h16x8 k8[4], v8[4];
    #pragma unroll
    for (int i = 0; i < 4; ++i) k8[i] = *((const h16x8*)kp + i);
    #pragma unroll
    for (int i = 0; i < 4; ++i) v8[i] = *((const h16x8*)(kp + 256) + i);

    float d = 0.0f;
#if __has_builtin(__builtin_amdgcn_fdot2)
    #pragma unroll
    for (int i = 0; i < 4; ++i) {
      #pragma unroll
      for (int p = 0; p < 4; ++p) {
        h16x2 ka = { k8[i][2*p], k8[i][2*p+1] };
        h16x2 qa = { q8[i][2*p], q8[i][2*p+1] };
        d = __builtin_amdgcn_fdot2(ka, qa, d, false);
      }
    }
#else
    #pragma unroll
    for (int i = 0; i < 4; ++i)
      #pragma unroll
      for (int e = 0; e < 8; ++e)
        d += (float)k8[i][e] * (float)q8[i][e];
#endif
    float p = __expf(d + pos[m]);
    l += p;
    #pragma unroll
    for (int i = 0; i < 4; ++i)
      #pragma unroll
      for (int e = 0; e < 8; ++e)
        o[i * 8 + e] += p * (float)v8[i][e];   // v_fma_mix
  }

  // reduce across the 8 neighbor-groups (same h)
  #pragma unroll
  for (int off = 8; off < 64; off <<= 1) {
    l += __shfl_xor(l, off);
    #pragma unroll
    for (int c = 0; c < 32; ++c) o[c] += __shfl_xor(o[c], off);
  }

  if (n == 0) {
    float inv = 1.0f / l;
    bf16* orow = out + (size_t)token * 256 + h * 32;
    #pragma unroll
    for (int c8 = 0; c8 < 4; ++c8) {
      bf16x8 t;
      #pragma unroll
      for (int e = 0; e < 8; ++e) t[e] = (bf16)(o[c8 * 8 + e] * inv);
      *(bf16x8*)(orow + c8 * 8) = t;
    }
  }
}

// ---------------- host launcher ----------------
extern "C" void kernel_launch(void* const* d_in, const int* in_sizes, int n_in,
                              void* d_out, int out_size, void* d_ws, size_t ws_size,
                              hipStream_t stream)
{
  (void)in_sizes; (void)n_in; (void)out_size; (void)ws_size;
  const float* feat         = (const float*)d_in[0];
  const float* cluster_mask = (const float*)d_in[1];
  const float* pre_table    = (const float*)d_in[2];
  const float* norm1_w      = (const float*)d_in[3];
  const float* norm1_b      = (const float*)d_in[4];
  const float* q_w    = (const float*)d_in[5];
  const float* q_b    = (const float*)d_in[6];
  const float* kv_w   = (const float*)d_in[7];
  const float* kv_b   = (const float*)d_in[8];
  const float* blank_k = (const float*)d_in[9];
  const float* blank_v = (const float*)d_in[10];
  const float* pe_w   = (const float*)d_in[11];
  const float* pe_b   = (const float*)d_in[12];
  const float* proj_w = (const float*)d_in[13];
  const float* proj_b = (const float*)d_in[14];
  const float* norm2_w = (const float*)d_in[15];
  const float* norm2_b = (const float*)d_in[16];
  const float* fc1_w  = (const float*)d_in[17];
  const float* fc1_b  = (const float*)d_in[18];
  const float* fc2_w  = (const float*)d_in[19];
  const float* fc2_b  = (const float*)d_in[20];
  const int* member_idx = (const int*)d_in[21];
  const int* pe_idx     = (const int*)d_in[22];

  char* ws = (char*)d_ws;
  size_t off = 0;
  auto alloc = [&](size_t bytes) -> void* {
    void* p = ws + off; off += (bytes + 255) & ~(size_t)255; return p;
  };
  bf16*  wqkv  = (bf16*)alloc(768 * 256 * sizeof(bf16));
  bf16*  wproj = (bf16*)alloc(256 * 256 * sizeof(bf16));
  bf16*  wfc1  = (bf16*)alloc(512 * 256 * sizeof(bf16));
  bf16*  wfc2  = (bf16*)alloc(256 * 512 * sizeof(bf16));
  float* qscale = (float*)alloc(768 * sizeof(float));
  float* qbias  = (float*)alloc(768 * sizeof(float));
  h16*   qf    = (h16*)alloc((size_t)8192 * 256 * sizeof(h16));
  h16*   kvf   = (h16*)alloc((size_t)8192 * 512 * sizeof(h16));
  bf16*  y1    = (bf16*)alloc((size_t)8192 * 512 * sizeof(bf16));
  bf16*  attnb = (bf16*)alloc((size_t)8192 * 256 * sizeof(bf16));
  float* feat2 = (float*)alloc((size_t)8192 * 256 * sizeof(float));
  float* posm  = (float*)alloc((size_t)8192 * 48 * 8 * sizeof(float));
  float* outf = (float*)d_out;

  // 1: prep + posm (fused)
  prep_posm_kernel<<<dim3(2304), dim3(256), 0, stream>>>(
      q_w, kv_w, proj_w, fc1_w, fc2_w, q_b, kv_b,
      wqkv, wproj, wfc1, wfc2, qscale, qbias,
      pe_idx, cluster_mask, pre_table, pe_w, pe_b, posm);
  // 2: LN1 + QKV (fused), split f16 q/kv epilogue
  gemm_bt<4, 256, true><<<dim3(128, 12), dim3(256), 0, stream>>>(
      feat, wqkv, 768, norm1_w, norm1_b, qscale, qbias,
      (const float*)nullptr, 0, (float*)nullptr, (bf16*)nullptr, qf, kvf);
  // 3: attention
  attn_kernel<<<dim3(2048), dim3(256), 0, stream>>>(
      qf, kvf, member_idx, posm, blank_k, blank_v, attnb);
  // 4: proj + residual -> feat2 (f32)
  gemm_bt<2, 256, false><<<dim3(128, 8), dim3(256), 0, stream>>>(
      attnb, wproj, 256, (const float*)nullptr, (const float*)nullptr,
      (const float*)nullptr, proj_b, feat, 0,
      feat2, (bf16*)nullptr, (h16*)nullptr, (h16*)nullptr);
  // 5: LN2 + fc1 (fused) + gelu -> y1 (bf16)
  gemm_bt<4, 256, true><<<dim3(128, 8), dim3(256), 0, stream>>>(
      feat2, wfc1, 512, norm2_w, norm2_b, (const float*)nullptr, fc1_b,
      (const float*)nullptr, 1, (float*)nullptr, y1, (h16*)nullptr, (h16*)nullptr);
  // 6: fc2 + residual -> d_out (f32)
  gemm_bt<2, 512, false><<<dim3(128, 8), dim3(256), 0, stream>>>(
      y1, wfc2, 256, (const float*)nullptr, (const float*)nullptr,
      (const float*)nullptr, fc2_b, feat2, 0,
      outf, (bf16*)nullptr, (h16*)nullptr, (h16*)nullptr);
}

// Round 12
// 113.135 us; speedup vs baseline: 4.2705x; 1.4183x over previous
//
#include <hip/hip_runtime.h>
#include <hip/hip_bf16.h>
#include <hip/hip_fp8.h>
#include <cstdint>
#include <cstddef>

typedef __bf16 bf16;
typedef bf16 bf16x4 __attribute__((ext_vector_type(4)));
typedef bf16 bf16x8 __attribute__((ext_vector_type(8)));
typedef float f32x4 __attribute__((ext_vector_type(4)));
typedef float f32x2 __attribute__((ext_vector_type(2)));

__device__ __forceinline__ float fp8_to_f32(uint8_t b) {
  __hip_fp8_e4m3 t; t.__x = (__hip_fp8_storage_t)b; return (float)t;
}
__device__ __forceinline__ uint8_t f32_to_fp8(float v) {
  __hip_fp8_e4m3 t(v); return (uint8_t)t.__x;
}
__device__ __forceinline__ void cvt4_fp8(int w, float* f) {
#if __has_builtin(__builtin_amdgcn_cvt_pk_f32_fp8)
  f32x2 a = __builtin_amdgcn_cvt_pk_f32_fp8(w, false);
  f32x2 b = __builtin_amdgcn_cvt_pk_f32_fp8(w, true);
  f[0] = a[0]; f[1] = a[1]; f[2] = b[0]; f[3] = b[1];
#else
  f[0] = fp8_to_f32((uint8_t)w);
  f[1] = fp8_to_f32((uint8_t)(w >> 8));
  f[2] = fp8_to_f32((uint8_t)(w >> 16));
  f[3] = fp8_to_f32((uint8_t)(w >> 24));
#endif
}

// ---------------- fused prep (weights->bf16) + posm (pe gather) ----------------
// kv activation col 256+j: j<256 -> k[h=j>>5][c=j&31]; j>=256 -> v[h][c].
__device__ __forceinline__ int kv_perm_to_orig(int j) {
  int jj = j & 255, h = jj >> 5, c = jj & 31;
  return h * 64 + ((j >> 8) ? 32 : 0) + c;
}

__global__ __launch_bounds__(256) void prep_posm_kernel(
    const float* __restrict__ q_w, const float* __restrict__ kv_w,
    const float* __restrict__ proj_w, const float* __restrict__ fc1_w,
    const float* __restrict__ fc2_w, const float* __restrict__ q_b,
    const float* __restrict__ kv_b,
    bf16* __restrict__ wqkv, bf16* __restrict__ wproj,
    bf16* __restrict__ wfc1, bf16* __restrict__ wfc2,
    float* __restrict__ qscale, float* __restrict__ qbias,
    const int* __restrict__ pe_idx,
    const float* __restrict__ cluster_mask,
    const float* __restrict__ pre_table,
    const float* __restrict__ pe_w, const float* __restrict__ pe_b,
    float* __restrict__ posm)
{
  const int b = blockIdx.x;
  if (b < 768) {
    int i = b * 256 + threadIdx.x;
    if (i < 196608) {
      int row = i >> 8, col = i & 255;
      float v;
      if (row < 256) v = q_w[i];
      else           v = kv_w[kv_perm_to_orig(row - 256) * 256 + col];
      wqkv[i] = (bf16)v;
    }
    if (i < 65536)  wproj[i] = (bf16)proj_w[i];
    if (i < 131072) { wfc1[i] = (bf16)fc1_w[i]; wfc2[i] = (bf16)fc2_w[i]; }
    if (i < 768) {
      const float s = 0.17677669529663687f;  // 1/sqrt(32)
      if (i < 256) { qscale[i] = s;    qbias[i] = q_b[i] * s; }
      else         { qscale[i] = 1.0f; qbias[i] = kv_b[kv_perm_to_orig(i - 256)]; }
    }
  } else {
    int i = (b - 768) * 256 + threadIdx.x;   // (token, j) flat, < 393216
    int pj = pe_idx[i];
    const float* pt = pre_table + (size_t)pj * 5;
    float p0 = pt[0], p1 = pt[1], p2 = pt[2], p3 = pt[3], p4 = pt[4];
    float mk = (1.0f - cluster_mask[i]) * -100.0f;
    f32x4 lo, hi;
    #pragma unroll
    for (int h = 0; h < 8; ++h) {
      float v = p0 * pe_w[h*5+0] + p1 * pe_w[h*5+1] + p2 * pe_w[h*5+2]
              + p3 * pe_w[h*5+3] + p4 * pe_w[h*5+4] + pe_b[h] + mk;
      if (h < 4) lo[h] = v; else hi[h-4] = v;
    }
    *((f32x4*)(posm + (size_t)i * 8))     = lo;
    *((f32x4*)(posm + (size_t)i * 8 + 4)) = hi;
  }
}

// ---------------- layernorm: one wave per 256-elem row -> bf16 ----------------
__global__ __launch_bounds__(256) void ln_kernel(
    const float* __restrict__ in, const float* __restrict__ w,
    const float* __restrict__ b, bf16* __restrict__ out)
{
  const int wv = threadIdx.x >> 6, lane = threadIdx.x & 63;
  const int row = blockIdx.x * 4 + wv;
  f32x4 v = *((const f32x4*)(in + (size_t)row * 256) + lane);
  float s  = v[0] + v[1] + v[2] + v[3];
  float s2 = v[0]*v[0] + v[1]*v[1] + v[2]*v[2] + v[3]*v[3];
  #pragma unroll
  for (int o = 1; o < 64; o <<= 1) { s += __shfl_xor(s, o); s2 += __shfl_xor(s2, o); }
  float mu = s * (1.0f / 256.0f);
  float var = s2 * (1.0f / 256.0f) - mu * mu;
  float rstd = rsqrtf(var + 1e-5f);
  f32x4 wv4 = *((const f32x4*)w + lane);
  f32x4 bv4 = *((const f32x4*)b + lane);
  bf16x4 o4;
  o4[0] = (bf16)((v[0] - mu) * rstd * wv4[0] + bv4[0]);
  o4[1] = (bf16)((v[1] - mu) * rstd * wv4[1] + bv4[1]);
  o4[2] = (bf16)((v[2] - mu) * rstd * wv4[2] + bv4[2]);
  o4[3] = (bf16)((v[3] - mu) * rstd * wv4[3] + bv4[3]);
  *((bf16x4*)(out + (size_t)row * 256) + lane) = o4;
}

// ---------------- GEMM: C(M,N) = A(M,K) * B(N,K)^T — barrier-free K-loop ----------------
template<int NF, int K>
__global__ __launch_bounds__(256) void gemm_bt(
    const bf16* __restrict__ A, const bf16* __restrict__ B,
    int N,
    const float* __restrict__ scale, const float* __restrict__ bias,
    const float* __restrict__ residual, int do_gelu,
    float* __restrict__ outf, bf16* __restrict__ outh,
    bf16* __restrict__ outq, uint8_t* __restrict__ outkv)
{
  constexpr int CN = NF * 16;
  constexpr int SPI = 64 / CN;
  __shared__ __align__(16) bf16 ldsB[K / 8][CN][8];
  const int tid = threadIdx.x;
  const int w = tid >> 6, lane = tid & 63;
  const int part = lane >> 4, r16 = lane & 15;
  const int rowBase = blockIdx.x * 64 + w * 16;
  const int colBase = blockIdx.y * CN;

  for (int s = w * SPI; s < K / 8; s += 4 * SPI) {
    const bf16* src = B + (size_t)(colBase + (lane & (CN - 1))) * K + (s + lane / CN) * 8;
    __builtin_amdgcn_global_load_lds(
        (const __attribute__((address_space(1))) uint32_t*)src,
        (__attribute__((address_space(3))) uint32_t*)&ldsB[s][0][0], 16, 0, 0);
  }

  f32x4 acc[NF] = {};
  const bf16* Aw = A + (size_t)(rowBase + r16) * K + part * 8;
  __syncthreads();

  #pragma unroll
  for (int p2 = 0; p2 < K / 32; ++p2) {
    bf16x8 af = *(const bf16x8*)(Aw + p2 * 32);
    bf16x8 bfr[NF];
    #pragma unroll
    for (int fn = 0; fn < NF; ++fn)
      bfr[fn] = *(const bf16x8*)&ldsB[p2 * 4 + part][fn * 16 + r16][0];
    #pragma unroll
    for (int fn = 0; fn < NF; ++fn)
      acc[fn] = __builtin_amdgcn_mfma_f32_16x16x32_bf16(af, bfr[fn], acc[fn], 0, 0, 0);
  }

  #pragma unroll
  for (int fn = 0; fn < NF; ++fn)
  #pragma unroll
  for (int r = 0; r < 4; ++r) {
    int row = rowBase + part * 4 + r;
    int col = colBase + fn * 16 + r16;
    float v = acc[fn][r];
    if (scale)    v *= scale[col];
    if (bias)     v += bias[col];
    if (do_gelu)  v = 0.5f * v * (1.0f + erff(v * 0.70710678118654752f));
    if (residual) v += residual[(size_t)row * N + col];
    if (outq) {
      if (col < 256) outq[(size_t)row * 256 + col] = (bf16)v;
      else           outkv[(size_t)row * 512 + (col - 256)] = f32_to_fp8(v);
    } else if (outf) {
      outf[(size_t)row * N + col] = v;
    } else {
      outh[(size_t)row * N + col] = (bf16)v;
    }
  }
}

// ---------------- attention v2b: wave per token, lane = (n:4, h:8, cb:2) ----------------
// 16 channels/lane -> q[16]+o[16] f32 (half of v2's register state), same fp8 gathers.
// Dot combined across the cb pair via shfl_xor(1); final reduce across n via xor 16,32.
__global__ __launch_bounds__(256) void attn_kernel(
    const bf16* __restrict__ qb,
    const uint8_t* __restrict__ kvf8,
    const int* __restrict__ member_idx,
    const float* __restrict__ posm,
    const float* __restrict__ blank_k, const float* __restrict__ blank_v,
    bf16* __restrict__ out)
{
  const int wv = threadIdx.x >> 6, lane = threadIdx.x & 63;
  const int token = blockIdx.x * 4 + wv;
  const int bb = token >> 12;
  const int n = lane >> 4;            // neighbor group 0..3
  const int hc = lane & 15;
  const int h = hc >> 1, cb = hc & 1;
  const int ch0 = h * 32 + cb * 16;   // channel base

  // q[16] f32
  float q[16];
  {
    const bf16* qrow = qb + (size_t)token * 256 + ch0;
    #pragma unroll
    for (int c8 = 0; c8 < 2; ++c8) {
      bf16x8 t = *(const bf16x8*)(qrow + c8 * 8);
      #pragma unroll
      for (int e = 0; e < 8; ++e) q[c8 * 8 + e] = (float)t[e];
    }
  }

  int   midx[12];
  float pos[12];
  #pragma unroll
  for (int m = 0; m < 12; ++m) {
    midx[m] = member_idx[(size_t)token * 48 + m * 4 + n];
    pos[m]  = posm[(size_t)token * 384 + (m * 4 + n) * 8 + h];
  }

  float l = 0.0f, o[16] = {};
  {  // blank token seeds group n==0
    float db = 0.0f;
    #pragma unroll
    for (int c = 0; c < 16; ++c) db += q[c] * blank_k[ch0 + c];
    db += __shfl_xor(db, 1);
    float pb = __expf(db);
    if (n == 0) {
      l = pb;
      #pragma unroll
      for (int c = 0; c < 16; ++c) o[c] = pb * blank_v[ch0 + c];
    }
  }

  const uint8_t* kvb = kvf8 + (size_t)(bb * 4096) * 512;
  #pragma unroll
  for (int m = 0; m < 12; ++m) {
    const uint8_t* kp = kvb + (size_t)midx[m] * 512 + ch0;
    int4 kw = *(const int4*)kp;          // k[ch0..ch0+15]
    int4 vw = *(const int4*)(kp + 256);  // v[ch0..ch0+15]

    float kf[4];
    float d = 0.0f;
    cvt4_fp8(kw.x, kf);
    #pragma unroll
    for (int c = 0; c < 4; ++c) d += q[c] * kf[c];
    cvt4_fp8(kw.y, kf);
    #pragma unroll
    for (int c = 0; c < 4; ++c) d += q[4 + c] * kf[c];
    cvt4_fp8(kw.z, kf);
    #pragma unroll
    for (int c = 0; c < 4; ++c) d += q[8 + c] * kf[c];
    cvt4_fp8(kw.w, kf);
    #pragma unroll
    for (int c = 0; c < 4; ++c) d += q[12 + c] * kf[c];

    d += __shfl_xor(d, 1);               // combine the two half-channel lanes
    float p = __expf(d + pos[m]);
    l += p;

    float vf[4];
    cvt4_fp8(vw.x, vf);
    #pragma unroll
    for (int c = 0; c < 4; ++c) o[c] += p * vf[c];
    cvt4_fp8(vw.y, vf);
    #pragma unroll
    for (int c = 0; c < 4; ++c) o[4 + c] += p * vf[c];
    cvt4_fp8(vw.z, vf);
    #pragma unroll
    for (int c = 0; c < 4; ++c) o[8 + c] += p * vf[c];
    cvt4_fp8(vw.w, vf);
    #pragma unroll
    for (int c = 0; c < 4; ++c) o[12 + c] += p * vf[c];
  }

  // reduce across the 4 neighbor groups (lanes differing in bits 4,5)
  l += __shfl_xor(l, 16); l += __shfl_xor(l, 32);
  #pragma unroll
  for (int c = 0; c < 16; ++c) {
    o[c] += __shfl_xor(o[c], 16);
    o[c] += __shfl_xor(o[c], 32);
  }

  if (n == 0) {
    float inv = 1.0f / l;
    bf16* orow = out + (size_t)token * 256 + ch0;
    #pragma unroll
    for (int c8 = 0; c8 < 2; ++c8) {
      bf16x8 t;
      #pragma unroll
      for (int e = 0; e < 8; ++e) t[e] = (bf16)(o[c8 * 8 + e] * inv);
      *(bf16x8*)(orow + c8 * 8) = t;
    }
  }
}

// ---------------- host launcher ----------------
extern "C" void kernel_launch(void* const* d_in, const int* in_sizes, int n_in,
                              void* d_out, int out_size, void* d_ws, size_t ws_size,
                              hipStream_t stream)
{
  (void)in_sizes; (void)n_in; (void)out_size; (void)ws_size;
  const float* feat         = (const float*)d_in[0];
  const float* cluster_mask = (const float*)d_in[1];
  const float* pre_table    = (const float*)d_in[2];
  const float* norm1_w      = (const float*)d_in[3];
  const float* norm1_b      = (const float*)d_in[4];
  const float* q_w    = (const float*)d_in[5];
  const float* q_b    = (const float*)d_in[6];
  const float* kv_w   = (const float*)d_in[7];
  const float* kv_b   = (const float*)d_in[8];
  const float* blank_k = (const float*)d_in[9];
  const float* blank_v = (const float*)d_in[10];
  const float* pe_w   = (const float*)d_in[11];
  const float* pe_b   = (const float*)d_in[12];
  const float* proj_w = (const float*)d_in[13];
  const float* proj_b = (const float*)d_in[14];
  const float* norm2_w = (const float*)d_in[15];
  const float* norm2_b = (const float*)d_in[16];
  const float* fc1_w  = (const float*)d_in[17];
  const float* fc1_b  = (const float*)d_in[18];
  const float* fc2_w  = (const float*)d_in[19];
  const float* fc2_b  = (const float*)d_in[20];
  const int* member_idx = (const int*)d_in[21];
  const int* pe_idx     = (const int*)d_in[22];

  char* ws = (char*)d_ws;
  size_t off = 0;
  auto alloc = [&](size_t bytes) -> void* {
    void* p = ws + off; off += (bytes + 255) & ~(size_t)255; return p;
  };
  bf16*  wqkv  = (bf16*)alloc(768 * 256 * sizeof(bf16));
  bf16*  wproj = (bf16*)alloc(256 * 256 * sizeof(bf16));
  bf16*  wfc1  = (bf16*)alloc(512 * 256 * sizeof(bf16));
  bf16*  wfc2  = (bf16*)alloc(256 * 512 * sizeof(bf16));
  float* qscale = (float*)alloc(768 * sizeof(float));
  float* qbias  = (float*)alloc(768 * sizeof(float));
  bf16*    xbuf = (bf16*)alloc((size_t)8192 * 256 * sizeof(bf16));
  bf16*    qb   = (bf16*)alloc((size_t)8192 * 256 * sizeof(bf16));
  uint8_t* kvf8 = (uint8_t*)alloc((size_t)8192 * 512);
  bf16*    y1   = (bf16*)alloc((size_t)8192 * 512 * sizeof(bf16));
  bf16*  attnb = (bf16*)alloc((size_t)8192 * 256 * sizeof(bf16));
  float* feat2 = (float*)alloc((size_t)8192 * 256 * sizeof(float));
  float* posm  = (float*)alloc((size_t)8192 * 48 * 8 * sizeof(float));
  float* outf = (float*)d_out;

  // 1: prep + posm (fused)
  prep_posm_kernel<<<dim3(2304), dim3(256), 0, stream>>>(
      q_w, kv_w, proj_w, fc1_w, fc2_w, q_b, kv_b,
      wqkv, wproj, wfc1, wfc2, qscale, qbias,
      pe_idx, cluster_mask, pre_table, pe_w, pe_b, posm);
  // 2: LN1
  ln_kernel<<<dim3(2048), dim3(256), 0, stream>>>(feat, norm1_w, norm1_b, xbuf);
  // 3: QKV, split epilogue -> q (bf16) + kv (fp8)
  gemm_bt<4, 256><<<dim3(128, 12), dim3(256), 0, stream>>>(
      xbuf, wqkv, 768, qscale, qbias, (const float*)nullptr, 0,
      (float*)nullptr, (bf16*)nullptr, qb, kvf8);
  // 4: attention
  attn_kernel<<<dim3(2048), dim3(256), 0, stream>>>(
      qb, kvf8, member_idx, posm, blank_k, blank_v, attnb);
  // 5: proj + residual -> feat2 (f32)
  gemm_bt<2, 256><<<dim3(128, 8), dim3(256), 0, stream>>>(
      attnb, wproj, 256, (const float*)nullptr, proj_b,
      feat, 0, feat2, (bf16*)nullptr, (bf16*)nullptr, (uint8_t*)nullptr);
  // 6: LN2
  ln_kernel<<<dim3(2048), dim3(256), 0, stream>>>(feat2, norm2_w, norm2_b, xbuf);
  // 7: fc1 + gelu -> y1 (bf16)
  gemm_bt<4, 256><<<dim3(128, 8), dim3(256), 0, stream>>>(
      xbuf, wfc1, 512, (const float*)nullptr, fc1_b,
      (const float*)nullptr, 1, (float*)nullptr, y1, (bf16*)nullptr, (uint8_t*)nullptr);
  // 8: fc2 + residual -> d_out (f32)
  gemm_bt<2, 512><<<dim3(128, 8), dim3(256), 0, stream>>>(
      y1, wfc2, 256, (const float*)nullptr, fc2_b,
      feat2, 0, outf, (bf16*)nullptr, (bf16*)nullptr, (uint8_t*)nullptr);
}

// Round 13
// 111.090 us; speedup vs baseline: 4.3490x; 1.0184x over previous
//
#include <hip/hip_runtime.h>
#include <hip/hip_bf16.h>
#include <hip/hip_fp8.h>
#include <cstdint>
#include <cstddef>

typedef __bf16 bf16;
typedef bf16 bf16x4 __attribute__((ext_vector_type(4)));
typedef bf16 bf16x8 __attribute__((ext_vector_type(8)));
typedef float f32x4 __attribute__((ext_vector_type(4)));
typedef float f32x2 __attribute__((ext_vector_type(2)));
typedef _Float16 h16;

__device__ __forceinline__ float fp8_to_f32(uint8_t b) {
  __hip_fp8_e4m3 t; t.__x = (__hip_fp8_storage_t)b; return (float)t;
}
__device__ __forceinline__ uint8_t f32_to_fp8(float v) {
  __hip_fp8_e4m3 t(v); return (uint8_t)t.__x;
}
__device__ __forceinline__ void cvt4_fp8(int w, float* f) {
#if __has_builtin(__builtin_amdgcn_cvt_pk_f32_fp8)
  f32x2 a = __builtin_amdgcn_cvt_pk_f32_fp8(w, false);
  f32x2 b = __builtin_amdgcn_cvt_pk_f32_fp8(w, true);
  f[0] = a[0]; f[1] = a[1]; f[2] = b[0]; f[3] = b[1];
#else
  f[0] = fp8_to_f32((uint8_t)w);
  f[1] = fp8_to_f32((uint8_t)(w >> 8));
  f[2] = fp8_to_f32((uint8_t)(w >> 16));
  f[3] = fp8_to_f32((uint8_t)(w >> 24));
#endif
}

// ---------------- fused prep (weights) + posm (pe gather, f16) + LN1 ----------------
// kv activation col 256+j: j<256 -> k[h=j>>5][c=j&31]; j>=256 -> v[h][c].
__device__ __forceinline__ int kv_perm_to_orig(int j) {
  int jj = j & 255, h = jj >> 5, c = jj & 31;
  return h * 64 + ((j >> 8) ? 32 : 0) + c;
}

__global__ __launch_bounds__(256) void prep_posm_ln_kernel(
    const float* __restrict__ q_w, const float* __restrict__ kv_w,
    const float* __restrict__ proj_w, const float* __restrict__ fc1_w,
    const float* __restrict__ fc2_w, const float* __restrict__ q_b,
    const float* __restrict__ kv_b,
    bf16* __restrict__ wqkv, bf16* __restrict__ wproj,
    bf16* __restrict__ wfc1, bf16* __restrict__ wfc2,
    float* __restrict__ qscale, float* __restrict__ qbias,
    const int* __restrict__ pe_idx,
    const float* __restrict__ cluster_mask,
    const float* __restrict__ pre_table,
    const float* __restrict__ pe_w, const float* __restrict__ pe_b,
    h16* __restrict__ posm,
    const float* __restrict__ feat,
    const float* __restrict__ norm1_w, const float* __restrict__ norm1_b,
    bf16* __restrict__ xbuf)
{
  const int b = blockIdx.x;
  if (b < 768) {
    int i = b * 256 + threadIdx.x;
    if (i < 196608) {
      int row = i >> 8, col = i & 255;
      float v;
      if (row < 256) v = q_w[i];
      else           v = kv_w[kv_perm_to_orig(row - 256) * 256 + col];
      wqkv[i] = (bf16)v;
    }
    if (i < 65536)  wproj[i] = (bf16)proj_w[i];
    if (i < 131072) { wfc1[i] = (bf16)fc1_w[i]; wfc2[i] = (bf16)fc2_w[i]; }
    if (i < 768) {
      const float s = 0.17677669529663687f;  // 1/sqrt(32)
      if (i < 256) { qscale[i] = s;    qbias[i] = q_b[i] * s; }
      else         { qscale[i] = 1.0f; qbias[i] = kv_b[kv_perm_to_orig(i - 256)]; }
    }
  } else if (b < 2304) {
    int i = (b - 768) * 256 + threadIdx.x;   // (token, j) flat, < 393216
    int pj = pe_idx[i];
    const float* pt = pre_table + (size_t)pj * 5;
    float p0 = pt[0], p1 = pt[1], p2 = pt[2], p3 = pt[3], p4 = pt[4];
    float mk = (1.0f - cluster_mask[i]) * -100.0f;
    h16 v8[8];
    #pragma unroll
    for (int h = 0; h < 8; ++h) {
      float v = p0 * pe_w[h*5+0] + p1 * pe_w[h*5+1] + p2 * pe_w[h*5+2]
              + p3 * pe_w[h*5+3] + p4 * pe_w[h*5+4] + pe_b[h] + mk;
      v8[h] = (h16)v;
    }
    *((uint4*)(posm + (size_t)i * 8)) = *(const uint4*)v8;
  } else {
    // LN1: one wave per 256-elem row
    const int wv = threadIdx.x >> 6, lane = threadIdx.x & 63;
    const int row = (b - 2304) * 4 + wv;
    f32x4 v = *((const f32x4*)(feat + (size_t)row * 256) + lane);
    float s  = v[0] + v[1] + v[2] + v[3];
    float s2 = v[0]*v[0] + v[1]*v[1] + v[2]*v[2] + v[3]*v[3];
    #pragma unroll
    for (int o = 1; o < 64; o <<= 1) { s += __shfl_xor(s, o); s2 += __shfl_xor(s2, o); }
    float mu = s * (1.0f / 256.0f);
    float var = s2 * (1.0f / 256.0f) - mu * mu;
    float rstd = rsqrtf(var + 1e-5f);
    f32x4 wv4 = *((const f32x4*)norm1_w + lane);
    f32x4 bv4 = *((const f32x4*)norm1_b + lane);
    bf16x4 o4;
    o4[0] = (bf16)((v[0] - mu) * rstd * wv4[0] + bv4[0]);
    o4[1] = (bf16)((v[1] - mu) * rstd * wv4[1] + bv4[1]);
    o4[2] = (bf16)((v[2] - mu) * rstd * wv4[2] + bv4[2]);
    o4[3] = (bf16)((v[3] - mu) * rstd * wv4[3] + bv4[3]);
    *((bf16x4*)(xbuf + (size_t)row * 256) + lane) = o4;
  }
}

// ---------------- layernorm (standalone, for LN2) ----------------
__global__ __launch_bounds__(256) void ln_kernel(
    const float* __restrict__ in, const float* __restrict__ w,
    const float* __restrict__ b, bf16* __restrict__ out)
{
  const int wv = threadIdx.x >> 6, lane = threadIdx.x & 63;
  const int row = blockIdx.x * 4 + wv;
  f32x4 v = *((const f32x4*)(in + (size_t)row * 256) + lane);
  float s  = v[0] + v[1] + v[2] + v[3];
  float s2 = v[0]*v[0] + v[1]*v[1] + v[2]*v[2] + v[3]*v[3];
  #pragma unroll
  for (int o = 1; o < 64; o <<= 1) { s += __shfl_xor(s, o); s2 += __shfl_xor(s2, o); }
  float mu = s * (1.0f / 256.0f);
  float var = s2 * (1.0f / 256.0f) - mu * mu;
  float rstd = rsqrtf(var + 1e-5f);
  f32x4 wv4 = *((const f32x4*)w + lane);
  f32x4 bv4 = *((const f32x4*)b + lane);
  bf16x4 o4;
  o4[0] = (bf16)((v[0] - mu) * rstd * wv4[0] + bv4[0]);
  o4[1] = (bf16)((v[1] - mu) * rstd * wv4[1] + bv4[1]);
  o4[2] = (bf16)((v[2] - mu) * rstd * wv4[2] + bv4[2]);
  o4[3] = (bf16)((v[3] - mu) * rstd * wv4[3] + bv4[3]);
  *((bf16x4*)(out + (size_t)row * 256) + lane) = o4;
}

// ---------------- GEMM: C(M,N) = A(M,K) * B(N,K)^T — barrier-free K-loop, FM=2 ----------------
// Wave owns 32 rows (2 A-frags) x CN cols (NF B-frags) -> 2*NF MFMA per NF+2 loads per
// K-step (vs NF per NF+1 at FM=1): halves LDS traffic per FLOP. Block = 4 waves = 128 rows.
template<int NF, int K>
__global__ __launch_bounds__(256) void gemm_bt(
    const bf16* __restrict__ A, const bf16* __restrict__ B,
    int N,
    const float* __restrict__ scale, const float* __restrict__ bias,
    const float* __restrict__ residual, int do_gelu,
    float* __restrict__ outf, bf16* __restrict__ outh,
    bf16* __restrict__ outq, uint8_t* __restrict__ outkv)
{
  constexpr int CN = NF * 16;
  constexpr int SPI = 64 / CN;
  __shared__ __align__(16) bf16 ldsB[K / 8][CN][8];
  const int tid = threadIdx.x;
  const int w = tid >> 6, lane = tid & 63;
  const int part = lane >> 4, r16 = lane & 15;
  const int rowBase = blockIdx.x * 128 + w * 32;
  const int colBase = blockIdx.y * CN;

  for (int s = w * SPI; s < K / 8; s += 4 * SPI) {
    const bf16* src = B + (size_t)(colBase + (lane & (CN - 1))) * K + (s + lane / CN) * 8;
    __builtin_amdgcn_global_load_lds(
        (const __attribute__((address_space(1))) uint32_t*)src,
        (__attribute__((address_space(3))) uint32_t*)&ldsB[s][0][0], 16, 0, 0);
  }

  f32x4 acc[2][NF] = {};
  const bf16* Aw0 = A + (size_t)(rowBase + r16) * K + part * 8;
  const bf16* Aw1 = A + (size_t)(rowBase + 16 + r16) * K + part * 8;
  __syncthreads();

  #pragma unroll
  for (int p2 = 0; p2 < K / 32; ++p2) {
    bf16x8 af0 = *(const bf16x8*)(Aw0 + p2 * 32);
    bf16x8 af1 = *(const bf16x8*)(Aw1 + p2 * 32);
    bf16x8 bfr[NF];
    #pragma unroll
    for (int fn = 0; fn < NF; ++fn)
      bfr[fn] = *(const bf16x8*)&ldsB[p2 * 4 + part][fn * 16 + r16][0];
    #pragma unroll
    for (int fn = 0; fn < NF; ++fn) {
      acc[0][fn] = __builtin_amdgcn_mfma_f32_16x16x32_bf16(af0, bfr[fn], acc[0][fn], 0, 0, 0);
      acc[1][fn] = __builtin_amdgcn_mfma_f32_16x16x32_bf16(af1, bfr[fn], acc[1][fn], 0, 0, 0);
    }
  }

  #pragma unroll
  for (int fm = 0; fm < 2; ++fm)
  #pragma unroll
  for (int fn = 0; fn < NF; ++fn)
  #pragma unroll
  for (int r = 0; r < 4; ++r) {
    int row = rowBase + fm * 16 + part * 4 + r;
    int col = colBase + fn * 16 + r16;
    float v = acc[fm][fn][r];
    if (scale)    v *= scale[col];
    if (bias)     v += bias[col];
    if (do_gelu)  v = 0.5f * v * (1.0f + erff(v * 0.70710678118654752f));
    if (residual) v += residual[(size_t)row * N + col];
    if (outq) {
      if (col < 256) outq[(size_t)row * 256 + col] = (bf16)v;
      else           outkv[(size_t)row * 512 + (col - 256)] = f32_to_fp8(v);
    } else if (outf) {
      outf[(size_t)row * N + col] = v;
    } else {
      outh[(size_t)row * N + col] = (bf16)v;
    }
  }
}

// ---------------- attention v2b: wave per token, lane = (n:4, h:8, cb:2) ----------------
__global__ __launch_bounds__(256) void attn_kernel(
    const bf16* __restrict__ qb,
    const uint8_t* __restrict__ kvf8,
    const int* __restrict__ member_idx,
    const h16* __restrict__ posm,
    const float* __restrict__ blank_k, const float* __restrict__ blank_v,
    bf16* __restrict__ out)
{
  const int wv = threadIdx.x >> 6, lane = threadIdx.x & 63;
  const int token = blockIdx.x * 4 + wv;
  const int bb = token >> 12;
  const int n = lane >> 4;            // neighbor group 0..3
  const int hc = lane & 15;
  const int h = hc >> 1, cb = hc & 1;
  const int ch0 = h * 32 + cb * 16;   // channel base

  float q[16];
  {
    const bf16* qrow = qb + (size_t)token * 256 + ch0;
    #pragma unroll
    for (int c8 = 0; c8 < 2; ++c8) {
      bf16x8 t = *(const bf16x8*)(qrow + c8 * 8);
      #pragma unroll
      for (int e = 0; e < 8; ++e) q[c8 * 8 + e] = (float)t[e];
    }
  }

  int   midx[12];
  float pos[12];
  #pragma unroll
  for (int m = 0; m < 12; ++m) {
    midx[m] = member_idx[(size_t)token * 48 + m * 4 + n];
    pos[m]  = (float)posm[(size_t)token * 384 + (m * 4 + n) * 8 + h];
  }

  float l = 0.0f, o[16] = {};
  {  // blank token seeds group n==0
    float db = 0.0f;
    #pragma unroll
    for (int c = 0; c < 16; ++c) db += q[c] * blank_k[ch0 + c];
    db += __shfl_xor(db, 1);
    float pb = __expf(db);
    if (n == 0) {
      l = pb;
      #pragma unroll
      for (int c = 0; c < 16; ++c) o[c] = pb * blank_v[ch0 + c];
    }
  }

  const uint8_t* kvb = kvf8 + (size_t)(bb * 4096) * 512;
  #pragma unroll
  for (int m = 0; m < 12; ++m) {
    const uint8_t* kp = kvb + (size_t)midx[m] * 512 + ch0;
    int4 kw = *(const int4*)kp;          // k[ch0..ch0+15]
    int4 vw = *(const int4*)(kp + 256);  // v[ch0..ch0+15]

    float kf[4];
    float d = 0.0f;
    cvt4_fp8(kw.x, kf);
    #pragma unroll
    for (int c = 0; c < 4; ++c) d += q[c] * kf[c];
    cvt4_fp8(kw.y, kf);
    #pragma unroll
    for (int c = 0; c < 4; ++c) d += q[4 + c] * kf[c];
    cvt4_fp8(kw.z, kf);
    #pragma unroll
    for (int c = 0; c < 4; ++c) d += q[8 + c] * kf[c];
    cvt4_fp8(kw.w, kf);
    #pragma unroll
    for (int c = 0; c < 4; ++c) d += q[12 + c] * kf[c];

    d += __shfl_xor(d, 1);               // combine the two half-channel lanes
    float p = __expf(d + pos[m]);
    l += p;

    float vf[4];
    cvt4_fp8(vw.x, vf);
    #pragma unroll
    for (int c = 0; c < 4; ++c) o[c] += p * vf[c];
    cvt4_fp8(vw.y, vf);
    #pragma unroll
    for (int c = 0; c < 4; ++c) o[4 + c] += p * vf[c];
    cvt4_fp8(vw.z, vf);
    #pragma unroll
    for (int c = 0; c < 4; ++c) o[8 + c] += p * vf[c];
    cvt4_fp8(vw.w, vf);
    #pragma unroll
    for (int c = 0; c < 4; ++c) o[12 + c] += p * vf[c];
  }

  // reduce across the 4 neighbor groups
  l += __shfl_xor(l, 16); l += __shfl_xor(l, 32);
  #pragma unroll
  for (int c = 0; c < 16; ++c) {
    o[c] += __shfl_xor(o[c], 16);
    o[c] += __shfl_xor(o[c], 32);
  }

  if (n == 0) {
    float inv = 1.0f / l;
    bf16* orow = out + (size_t)token * 256 + ch0;
    #pragma unroll
    for (int c8 = 0; c8 < 2; ++c8) {
      bf16x8 t;
      #pragma unroll
      for (int e = 0; e < 8; ++e) t[e] = (bf16)(o[c8 * 8 + e] * inv);
      *(bf16x8*)(orow + c8 * 8) = t;
    }
  }
}

// ---------------- host launcher ----------------
extern "C" void kernel_launch(void* const* d_in, const int* in_sizes, int n_in,
                              void* d_out, int out_size, void* d_ws, size_t ws_size,
                              hipStream_t stream)
{
  (void)in_sizes; (void)n_in; (void)out_size; (void)ws_size;
  const float* feat         = (const float*)d_in[0];
  const float* cluster_mask = (const float*)d_in[1];
  const float* pre_table    = (const float*)d_in[2];
  const float* norm1_w      = (const float*)d_in[3];
  const float* norm1_b      = (const float*)d_in[4];
  const float* q_w    = (const float*)d_in[5];
  const float* q_b    = (const float*)d_in[6];
  const float* kv_w   = (const float*)d_in[7];
  const float* kv_b   = (const float*)d_in[8];
  const float* blank_k = (const float*)d_in[9];
  const float* blank_v = (const float*)d_in[10];
  const float* pe_w   = (const float*)d_in[11];
  const float* pe_b   = (const float*)d_in[12];
  const float* proj_w = (const float*)d_in[13];
  const float* proj_b = (const float*)d_in[14];
  const float* norm2_w = (const float*)d_in[15];
  const float* norm2_b = (const float*)d_in[16];
  const float* fc1_w  = (const float*)d_in[17];
  const float* fc1_b  = (const float*)d_in[18];
  const float* fc2_w  = (const float*)d_in[19];
  const float* fc2_b  = (const float*)d_in[20];
  const int* member_idx = (const int*)d_in[21];
  const int* pe_idx     = (const int*)d_in[22];

  char* ws = (char*)d_ws;
  size_t off = 0;
  auto alloc = [&](size_t bytes) -> void* {
    void* p = ws + off; off += (bytes + 255) & ~(size_t)255; return p;
  };
  bf16*  wqkv  = (bf16*)alloc(768 * 256 * sizeof(bf16));
  bf16*  wproj = (bf16*)alloc(256 * 256 * sizeof(bf16));
  bf16*  wfc1  = (bf16*)alloc(512 * 256 * sizeof(bf16));
  bf16*  wfc2  = (bf16*)alloc(256 * 512 * sizeof(bf16));
  float* qscale = (float*)alloc(768 * sizeof(float));
  float* qbias  = (float*)alloc(768 * sizeof(float));
  bf16*    xbuf = (bf16*)alloc((size_t)8192 * 256 * sizeof(bf16));
  bf16*    qb   = (bf16*)alloc((size_t)8192 * 256 * sizeof(bf16));
  uint8_t* kvf8 = (uint8_t*)alloc((size_t)8192 * 512);
  bf16*    y1   = (bf16*)alloc((size_t)8192 * 512 * sizeof(bf16));
  bf16*  attnb = (bf16*)alloc((size_t)8192 * 256 * sizeof(bf16));
  float* feat2 = (float*)alloc((size_t)8192 * 256 * sizeof(float));
  h16*   posm  = (h16*)alloc((size_t)8192 * 48 * 8 * sizeof(h16));
  float* outf = (float*)d_out;

  // 1: prep + posm + LN1 (fused, independent inputs)
  prep_posm_ln_kernel<<<dim3(4352), dim3(256), 0, stream>>>(
      q_w, kv_w, proj_w, fc1_w, fc2_w, q_b, kv_b,
      wqkv, wproj, wfc1, wfc2, qscale, qbias,
      pe_idx, cluster_mask, pre_table, pe_w, pe_b, posm,
      feat, norm1_w, norm1_b, xbuf);
  // 2: QKV, split epilogue -> q (bf16) + kv (fp8). grid (64,12)=768 blocks
  gemm_bt<4, 256><<<dim3(64, 12), dim3(256), 0, stream>>>(
      xbuf, wqkv, 768, qscale, qbias, (const float*)nullptr, 0,
      (float*)nullptr, (bf16*)nullptr, qb, kvf8);
  // 3: attention
  attn_kernel<<<dim3(2048), dim3(256), 0, stream>>>(
      qb, kvf8, member_idx, posm, blank_k, blank_v, attnb);
  // 4: proj + residual -> feat2 (f32). grid (64,8)=512 blocks
  gemm_bt<2, 256><<<dim3(64, 8), dim3(256), 0, stream>>>(
      attnb, wproj, 256, (const float*)nullptr, proj_b,
      feat, 0, feat2, (bf16*)nullptr, (bf16*)nullptr, (uint8_t*)nullptr);
  // 5: LN2
  ln_kernel<<<dim3(2048), dim3(256), 0, stream>>>(feat2, norm2_w, norm2_b, xbuf);
  // 6: fc1 + gelu -> y1 (bf16). grid (64,8)=512 blocks
  gemm_bt<4, 256><<<dim3(64, 8), dim3(256), 0, stream>>>(
      xbuf, wfc1, 512, (const float*)nullptr, fc1_b,
      (const float*)nullptr, 1, (float*)nullptr, y1, (bf16*)nullptr, (uint8_t*)nullptr);
  // 7: fc2 + residual -> d_out (f32). grid (64,8)=512 blocks
  gemm_bt<2, 512><<<dim3(64, 8), dim3(256), 0, stream>>>(
      y1, wfc2, 256, (const float*)nullptr, fc2_b,
      feat2, 0, outf, (bf16*)nullptr, (bf16*)nullptr, (uint8_t*)nullptr);
}